// Round 15
// baseline (229.231 us; speedup 1.0000x reference)
//
#include <hip/hip_runtime.h>
#include <hip/hip_bf16.h>

#define GAT_N 8192
#define GAT_K 256
#define GAT_D 64
#define GAT_ALPHA 0.2f
#define GAT_FILL 1e-15f

typedef float f32x4 __attribute__((ext_vector_type(4)));
typedef short bf16x8 __attribute__((ext_vector_type(8)));

static __device__ __forceinline__ unsigned f2bf_u(float x) {
  unsigned u = __float_as_uint(x);
  u += 0x7FFFu + ((u >> 16) & 1u);
  return u >> 16;
}

// ---------------------------------------------------------------------------
// Kernel 1: register-tiled Wh = h @ W. Emits WhT_f in MFMA-FRAGMENT-TILED
// layout: frag(c,q,f) holds Wh rows d=q*16..+16, k-cols c*512+f*32..+32, as
// lane-linear 16B pieces: addr = c*65536 + q*16384 + f*1024
//                               + ((d&15) + 16*((k&31)>>3))*16 + (k&7)*2.
// k_pv then loads A-fragments as contiguous lane*16 (no gathers).
// ---------------------------------------------------------------------------
__global__ __launch_bounds__(256) void k_prep(const float* __restrict__ h,
                                              const float* __restrict__ W,
                                              const float* __restrict__ av,
                                              float* __restrict__ s_src,
                                              float* __restrict__ s_dst,
                                              short* __restrict__ WhT_f,
                                              float* __restrict__ bmax) {
  __shared__ short T[4][64][8];
  __shared__ float wmLds[4];
  const int tid = threadIdx.x;
  const int wv = tid >> 6, lane = tid & 63;
  const int r0 = blockIdx.x * 32 + wv * 8;  // 8 consecutive k-indices

  float acc[8], acc2[8];
#pragma unroll
  for (int r = 0; r < 8; ++r) { acc[r] = 0.f; acc2[r] = 0.f; }

  for (int kc = 0; kc < GAT_K; kc += 32) {
    float Wreg[32];
#pragma unroll
    for (int e = 0; e < 32; ++e) Wreg[e] = W[(size_t)(kc + e) * GAT_D + lane];
#pragma unroll
    for (int r = 0; r < 8; ++r) {
      const f32x4* h4 = (const f32x4*)(h + (size_t)(r0 + r) * GAT_K + kc);
#pragma unroll
      for (int q = 0; q < 8; ++q) {
        f32x4 hv = h4[q];
        acc[r] += hv[0] * Wreg[4 * q + 0];
        acc2[r] += hv[1] * Wreg[4 * q + 1];
        acc[r] += hv[2] * Wreg[4 * q + 2];
        acc2[r] += hv[3] * Wreg[4 * q + 3];
      }
    }
  }

  const float a_s = av[lane];
  const float a_d = av[64 + lane];
  float wmax = -3.0e38f;
#pragma unroll
  for (int r = 0; r < 8; ++r) {
    const float accf = acc[r] + acc2[r];
    T[wv][lane][r] = (short)f2bf_u(accf);
    float vs = accf * a_s, vd = accf * a_d;
#pragma unroll
    for (int off = 32; off > 0; off >>= 1) {
      vs += __shfl_xor(vs, off);
      vd += __shfl_xor(vd, off);
    }
    if (lane == 0) { s_src[r0 + r] = vs; s_dst[r0 + r] = vd; }
    wmax = fmaxf(wmax, vd);
  }
  // vt = Wh[k = r0..r0+7][d = lane]  (8 consecutive k for this d)
  bf16x8 vt = *(const bf16x8*)&T[wv][lane][0];
  {
    const int c = r0 >> 9, f = (r0 & 511) >> 5, kgr = (r0 & 31) >> 3;
    short* dst = WhT_f + (size_t)c * 32768 + (size_t)(lane >> 4) * 8192 +
                 f * 512 + ((lane & 15) + 16 * kgr) * 8;
    *(bf16x8*)dst = vt;
  }

  if (lane == 0) wmLds[wv] = wmax;
  __syncthreads();
  if (tid == 0) {
    bmax[blockIdx.x] = fmaxf(fmaxf(wmLds[0], wmLds[1]), fmaxf(wmLds[2], wmLds[3]));
  }
}

// ---------------------------------------------------------------------------
// Kernel 2 (k_stage): PURE STREAM. 512 blocks x 1024 thr (16 waves = 16 rows;
// 32 waves/CU). Read A row-wise (32B/lane), compute P = fixed-shift masked
// softmax numerator (1 exp/elem), write P in fragment-tiled layout
// (16B/lane pieces; L2 merges lines across the block's concurrent waves),
// accumulate row-sum l in f32. No LDS, no barriers, no gathers.
//   P_t[itile][c][f][lane16] : itile=i>>4, c=j>>9, f=(j&511)>>5,
//   lane16 = (i&15) + 16*((j&31)>>3), bytes (j&7)*2.
// ---------------------------------------------------------------------------
__global__ __launch_bounds__(1024) void k_stage(const float* __restrict__ A,
                                                const float* __restrict__ s_src,
                                                const float* __restrict__ s_dst,
                                                const float* __restrict__ bmax,
                                                char* __restrict__ P_t,
                                                float* __restrict__ l_arr) {
  const int tid = threadIdx.x;
  const int w = tid >> 6;    // wave = row-in-tile (0..15)
  const int tp = tid & 63;   // lane
  const int i0 = blockIdx.x * 16;
  const int row = i0 + w;

  // global max of s_dst from 256 per-block maxima
  float bm = fmaxf(fmaxf(bmax[tp], bmax[tp + 64]),
                   fmaxf(bmax[tp + 128], bmax[tp + 192]));
#pragma unroll
  for (int off = 32; off > 0; off >>= 1) bm = fmaxf(bm, __shfl_xor(bm, off));
  const float tmax = bm;

  const float sc = s_src[row];
  const float x0 = sc + tmax;
  const float m = fmaxf(fmaxf(x0, GAT_ALPHA * x0), GAT_FILL);
  const float e1 = sc - m;
  const float e2 = GAT_ALPHA * sc - m;
  const float ccv = __expf(GAT_FILL - m);

  const float* Ar = A + (size_t)row * GAT_N + tp * 8;
  const float* tr = s_dst + tp * 8;
  // fragment piece base for this thread: f = tp>>2, kg = tp&3
  char* Pb = P_t + (size_t)blockIdx.x * 262144 + (tp >> 2) * 1024 +
             ((w + 16 * (tp & 3)) << 4);

  float lsum = 0.f;
  for (int c = 0; c < 16; ++c) {
    const f32x4 a0 = *(const f32x4*)(Ar + c * 512);
    const f32x4 a1 = *(const f32x4*)(Ar + c * 512 + 4);
    const f32x4 t0 = *(const f32x4*)(tr + c * 512);
    const f32x4 t1 = *(const f32x4*)(tr + c * 512 + 4);
    float p[8];
#pragma unroll
    for (int e = 0; e < 4; ++e) {
      float arg = fmaxf(t0[e] + e1, fmaf(GAT_ALPHA, t0[e], e2));
      float pe = __expf(arg);
      p[e] = (a0[e] > 0.f) ? pe : ccv;
    }
#pragma unroll
    for (int e = 0; e < 4; ++e) {
      float arg = fmaxf(t1[e] + e1, fmaf(GAT_ALPHA, t1[e], e2));
      float pe = __expf(arg);
      p[4 + e] = (a1[e] > 0.f) ? pe : ccv;
    }
#pragma unroll
    for (int e = 0; e < 8; ++e) lsum += p[e];

    __hip_bfloat162 b0 = __float22bfloat162_rn(float2{p[0], p[1]});
    __hip_bfloat162 b1 = __float22bfloat162_rn(float2{p[2], p[3]});
    __hip_bfloat162 b2 = __float22bfloat162_rn(float2{p[4], p[5]});
    __hip_bfloat162 b3 = __float22bfloat162_rn(float2{p[6], p[7]});
    uint4 u;
    __builtin_memcpy(&u.x, &b0, 4);
    __builtin_memcpy(&u.y, &b1, 4);
    __builtin_memcpy(&u.z, &b2, 4);
    __builtin_memcpy(&u.w, &b3, 4);
    *(uint4*)(Pb + c * 16384) = u;
  }

#pragma unroll
  for (int off = 32; off > 0; off >>= 1) lsum += __shfl_xor(lsum, off);
  if (tp == 0) l_arr[row] = lsum;
}

// ---------------------------------------------------------------------------
// Kernel 3 (k_pv): fragment-direct GEMM  out[i][d] = (P @ Wh)[i][d] / l, ELU.
// 512 blocks x 256 thr (4 waves). A-frag = WhT_f (m=d), B-frag = P_t (n=i):
// BOTH load as contiguous lane*16B (1 KB/wave-instr, zero gathers, zero LDS
// in the main loop). Wave wv owns f in [4wv, 4wv+4) of every chunk (exact
// K-partition); 256 MFMA/wave. Cross-wave exact combine in epilogue.
// C/D (m89): col=lane&15 = n = i-sub, row = kg*4+reg = m = d-sub.
// ---------------------------------------------------------------------------
__global__ __launch_bounds__(256) void k_pv(const short* __restrict__ WhT_f,
                                            const char* __restrict__ P_t,
                                            const float* __restrict__ l_arr,
                                            float* __restrict__ out) {
  __shared__ float lds_o[4 * 16 * 65];  // [wave][i'][d] padded (+1 row stride)

  const int tid = threadIdx.x;
  const int wv = tid >> 6, lane = tid & 63;
  const int rsub = lane & 15, kg = lane >> 4;
  const int i0 = blockIdx.x * 16;

  f32x4 acc0 = {0.f, 0.f, 0.f, 0.f};
  f32x4 acc1 = {0.f, 0.f, 0.f, 0.f};
  f32x4 acc2 = {0.f, 0.f, 0.f, 0.f};
  f32x4 acc3 = {0.f, 0.f, 0.f, 0.f};

  const char* Pb = P_t + (size_t)blockIdx.x * 262144 + lane * 16;
  const short* Wb = WhT_f + lane * 8;

  for (int c = 0; c < 16; ++c) {
    const char* Pc = Pb + c * 16384;
    const short* Wc = Wb + (size_t)c * 32768;
#pragma unroll
    for (int fi = 0; fi < 4; ++fi) {
      const int f = wv * 4 + fi;
      bf16x8 bP = *(const bf16x8*)(Pc + f * 1024);
      const short* Wf = Wc + f * 512;
      bf16x8 a0 = *(const bf16x8*)(Wf + 0 * 8192);
      bf16x8 a1 = *(const bf16x8*)(Wf + 1 * 8192);
      bf16x8 a2 = *(const bf16x8*)(Wf + 2 * 8192);
      bf16x8 a3 = *(const bf16x8*)(Wf + 3 * 8192);
      acc0 = __builtin_amdgcn_mfma_f32_16x16x32_bf16(a0, bP, acc0, 0, 0, 0);
      acc1 = __builtin_amdgcn_mfma_f32_16x16x32_bf16(a1, bP, acc1, 0, 0, 0);
      acc2 = __builtin_amdgcn_mfma_f32_16x16x32_bf16(a2, bP, acc2, 0, 0, 0);
      acc3 = __builtin_amdgcn_mfma_f32_16x16x32_bf16(a3, bP, acc3, 0, 0, 0);
    }
  }

  // spill: thread (rsub,kg) reg r of quad q -> out[i0+rsub][q*16 + kg*4 + r]
#pragma unroll
  for (int r = 0; r < 4; ++r) {
    const int d = kg * 4 + r;
    lds_o[wv * 1040 + rsub * 65 + 0 * 16 + d] = acc0[r];
    lds_o[wv * 1040 + rsub * 65 + 1 * 16 + d] = acc1[r];
    lds_o[wv * 1040 + rsub * 65 + 2 * 16 + d] = acc2[r];
    lds_o[wv * 1040 + rsub * 65 + 3 * 16 + d] = acc3[r];
  }
  __syncthreads();

  for (int idx = tid; idx < 16 * GAT_D; idx += 256) {
    const int r = idx >> 6, d = idx & 63;
    float o = lds_o[0 * 1040 + r * 65 + d] + lds_o[1 * 1040 + r * 65 + d] +
              lds_o[2 * 1040 + r * 65 + d] + lds_o[3 * 1040 + r * 65 + d];
    float val = o / l_arr[i0 + r];
    out[(size_t)(i0 + r) * GAT_D + d] = (val > 0.f) ? val : (__expf(val) - 1.f);
  }
}

// ---------------------------------------------------------------------------
extern "C" void kernel_launch(void* const* d_in, const int* in_sizes, int n_in,
                              void* d_out, int out_size, void* d_ws, size_t ws_size,
                              hipStream_t stream) {
  const float* h = (const float*)d_in[0];
  const float* A = (const float*)d_in[1];
  const float* W = (const float*)d_in[2];
  const float* a = (const float*)d_in[3];
  float* out = (float*)d_out;

  // ws: [0,1K) bmax | [4K,+32K) s_src | [36864,+32K) s_dst | [69632,+1M) WhT_f
  //     [1179648,+32K) l_arr | [2097152,+128M) P_t
  const size_t need = 2097152 + (size_t)GAT_N * GAT_N * 2;
  if (ws_size < need) return;
  float* bmax = (float*)d_ws;
  float* s_src = (float*)((char*)d_ws + 4096);
  float* s_dst = (float*)((char*)d_ws + 36864);
  short* WhT_f = (short*)((char*)d_ws + 69632);
  float* l_arr = (float*)((char*)d_ws + 1179648);
  char* P_t = (char*)d_ws + 2097152;

  k_prep<<<dim3(256), dim3(256), 0, stream>>>(h, W, a, s_src, s_dst, WhT_f, bmax);
  k_stage<<<dim3(GAT_N / 16), dim3(1024), 0, stream>>>(A, s_src, s_dst, bmax,
                                                       P_t, l_arr);
  k_pv<<<dim3(GAT_N / 16), dim3(256), 0, stream>>>(WhT_f, P_t, l_arr, out);
}

// Round 16
// 117.211 us; speedup vs baseline: 1.9557x; 1.9557x over previous
//
#include <hip/hip_runtime.h>
#include <hip/hip_bf16.h>

#define GAT_N 8192
#define GAT_K 256
#define GAT_D 64
#define GAT_ALPHA 0.2f
#define GAT_FILL 1e-15f

typedef float f32x4 __attribute__((ext_vector_type(4)));
typedef short bf16x8 __attribute__((ext_vector_type(8)));

static __device__ __forceinline__ unsigned f2bf_u(float x) {
  unsigned u = __float_as_uint(x);
  u += 0x7FFFu + ((u >> 16) & 1u);
  return u >> 16;
}

static __device__ __forceinline__ float rfl(float x) {
  return __uint_as_float(__builtin_amdgcn_readfirstlane(__float_as_uint(x)));
}

// ---------------------------------------------------------------------------
// Kernel 1: register-tiled Wh = h @ W; emits WhT_f in MFMA-fragment-tiled
// layout (validated round 15): fragment(c=j>>9, dq=d>>4, kq=(j&511)>>5) is a
// contiguous 1 KB block; lane piece = ((d&15) + 16*((j&31)>>3))*16B.
// ---------------------------------------------------------------------------
__global__ __launch_bounds__(256) void k_prep(const float* __restrict__ h,
                                              const float* __restrict__ W,
                                              const float* __restrict__ av,
                                              float* __restrict__ s_src,
                                              float* __restrict__ s_dst,
                                              short* __restrict__ WhT_f,
                                              float* __restrict__ bmax) {
  __shared__ short T[4][64][8];
  __shared__ float wmLds[4];
  const int tid = threadIdx.x;
  const int wv = tid >> 6, lane = tid & 63;
  const int r0 = blockIdx.x * 32 + wv * 8;  // 8 consecutive k (=j) indices

  float acc[8], acc2[8];
#pragma unroll
  for (int r = 0; r < 8; ++r) { acc[r] = 0.f; acc2[r] = 0.f; }

  for (int kc = 0; kc < GAT_K; kc += 32) {
    float Wreg[32];
#pragma unroll
    for (int e = 0; e < 32; ++e) Wreg[e] = W[(size_t)(kc + e) * GAT_D + lane];
#pragma unroll
    for (int r = 0; r < 8; ++r) {
      const f32x4* h4 = (const f32x4*)(h + (size_t)(r0 + r) * GAT_K + kc);
#pragma unroll
      for (int q = 0; q < 8; ++q) {
        f32x4 hv = h4[q];
        acc[r] += hv[0] * Wreg[4 * q + 0];
        acc2[r] += hv[1] * Wreg[4 * q + 1];
        acc[r] += hv[2] * Wreg[4 * q + 2];
        acc2[r] += hv[3] * Wreg[4 * q + 3];
      }
    }
  }

  const float a_s = av[lane];
  const float a_d = av[64 + lane];
  float wmax = -3.0e38f;
#pragma unroll
  for (int r = 0; r < 8; ++r) {
    const float accf = acc[r] + acc2[r];
    T[wv][lane][r] = (short)f2bf_u(accf);
    float vs = accf * a_s, vd = accf * a_d;
#pragma unroll
    for (int off = 32; off > 0; off >>= 1) {
      vs += __shfl_xor(vs, off);
      vd += __shfl_xor(vd, off);
    }
    if (lane == 0) { s_src[r0 + r] = vs; s_dst[r0 + r] = vd; }
    wmax = fmaxf(wmax, vd);
  }
  bf16x8 vt = *(const bf16x8*)&T[wv][lane][0];
  {
    const int c = r0 >> 9, f = (r0 & 511) >> 5, kgr = (r0 & 31) >> 3;
    short* dst = WhT_f + (size_t)c * 32768 + (size_t)(lane >> 4) * 8192 +
                 f * 512 + ((lane & 15) + 16 * kgr) * 8;
    *(bf16x8*)dst = vt;
  }

  if (lane == 0) wmLds[wv] = wmax;
  __syncthreads();
  if (tid == 0) {
    bmax[blockIdx.x] = fmaxf(fmaxf(wmLds[0], wmLds[1]), fmaxf(wmLds[2], wmLds[3]));
  }
}

// ---------------------------------------------------------------------------
// Kernel 2 (k_attn): j-split one-shot blocks, minimal global line count.
//   grid = 8192 blocks (it = blk>>4 i-tile, jc = blk&15 j-chunk), 256 thr.
//   Stage: wave wv computes rows 4wv..4wv+3; A read as 1 KB-contiguous
//     wave-loads (16 lines/instr = minimum); P -> XOR-swizzled LDS [16][512].
//   MFMA: wave wv owns k-quads 4wv..4wv+3; A-op = WhT_f fragments
//     (contiguous 1 KB, used once); B-op = P from LDS; +ones-A for row-sum.
//   Combine 4 waves in LDS -> o_part[jc][it] (4 KB) + l_part. No loops,
//   no pipelines: block-level TLP hides all latency.
// ---------------------------------------------------------------------------
__global__ __launch_bounds__(256, 6) void k_attn(
    const float* __restrict__ A,
    const float* __restrict__ s_src,
    const float* __restrict__ s_dst,
    const short* __restrict__ WhT_f,
    const float* __restrict__ bmax,
    float* __restrict__ o_part,
    float* __restrict__ l_part) {
  __shared__ char smem[16896];  // P tile [0,16K); reuse: lds_o[4][16][65] | lds_l @16640

  const int tid = threadIdx.x;
  const int wv = tid >> 6, lane = tid & 63;
  const int rsub = lane & 15, kg = lane >> 4;
  const int it = blockIdx.x >> 4, jc = blockIdx.x & 15;
  const int i0 = it * 16, j0 = jc * 512;

  // global max of s_dst from 256 per-block maxima
  float bm = fmaxf(fmaxf(bmax[lane], bmax[lane + 64]),
                   fmaxf(bmax[lane + 128], bmax[lane + 192]));
#pragma unroll
  for (int off = 32; off > 0; off >>= 1) bm = fmaxf(bm, __shfl_xor(bm, off));
  const float tmax = bm;

  // ---- stage: rows 4wv..4wv+3, two 256-col halves each ----
  const float* Arow = A + (size_t)(i0 + 4 * wv) * GAT_N + j0 + lane * 4;
  const f32x4 t0 = *(const f32x4*)(s_dst + j0 + lane * 4);
  const f32x4 t1 = *(const f32x4*)(s_dst + j0 + 256 + lane * 4);

  f32x4 E1a, E2a, E1b, E2b;
#pragma unroll
  for (int e = 0; e < 4; ++e) {
    E1a[e] = __expf(t0[e]);
    E2a[e] = __expf(GAT_ALPHA * t0[e]);
    E1b[e] = __expf(t1[e]);
    E2b[e] = __expf(GAT_ALPHA * t1[e]);
  }

#pragma unroll
  for (int r = 0; r < 4; ++r) {
    const int row = 4 * wv + r;
    f32x4 av0 = *(const f32x4*)(Arow + (size_t)r * GAT_N);
    f32x4 av1 = *(const f32x4*)(Arow + (size_t)r * GAT_N + 256);
    const float sc = rfl(s_src[i0 + row]);
    const float x0 = sc + tmax;
    const float m = fmaxf(fmaxf(x0, GAT_ALPHA * x0), GAT_FILL);
    const float F1 = rfl(__expf(sc - m));
    const float F2 = rfl(__expf(GAT_ALPHA * sc - m));
    const float ns = -sc;
    const float cc = rfl(__expf(GAT_FILL - m));

    float p[4];
#pragma unroll
    for (int e = 0; e < 4; ++e) {
      float psel = (t0[e] >= ns) ? E1a[e] * F1 : E2a[e] * F2;
      p[e] = (av0[e] > 0.f) ? psel : cc;
    }
    __hip_bfloat162 pa = __float22bfloat162_rn(float2{p[0], p[1]});
    __hip_bfloat162 pb = __float22bfloat162_rn(float2{p[2], p[3]});
    uint2 w;
    __builtin_memcpy(&w.x, &pa, 4);
    __builtin_memcpy(&w.y, &pb, 4);
    *(uint2*)(&smem[(row << 10) + ((lane << 3) ^ ((row & 7) << 4))]) = w;

#pragma unroll
    for (int e = 0; e < 4; ++e) {
      float psel = (t1[e] >= ns) ? E1b[e] * F1 : E2b[e] * F2;
      p[e] = (av1[e] > 0.f) ? psel : cc;
    }
    pa = __float22bfloat162_rn(float2{p[0], p[1]});
    pb = __float22bfloat162_rn(float2{p[2], p[3]});
    __builtin_memcpy(&w.x, &pa, 4);
    __builtin_memcpy(&w.y, &pb, 4);
    *(uint2*)(&smem[(row << 10) + ((512 + (lane << 3)) ^ ((row & 7) << 4))]) = w;
  }
  __syncthreads();  // P tile ready

  // ---- MFMA: wave wv owns k-quads 4wv..4wv+3 ----
  bf16x8 ones;
#pragma unroll
  for (int e = 0; e < 8; ++e) ones[e] = (short)0x3F80;

  f32x4 acc0 = {0.f, 0.f, 0.f, 0.f};
  f32x4 acc1 = {0.f, 0.f, 0.f, 0.f};
  f32x4 acc2 = {0.f, 0.f, 0.f, 0.f};
  f32x4 acc3 = {0.f, 0.f, 0.f, 0.f};
  f32x4 accl = {0.f, 0.f, 0.f, 0.f};

  const short* Wb = WhT_f + (size_t)jc * 32768 + lane * 8;
#pragma unroll
  for (int q = 0; q < 4; ++q) {
    const int kq = wv * 4 + q;
    const int raddr = (rsub << 10) + (((kq << 6) | (kg << 4)) ^ ((rsub & 7) << 4));
    bf16x8 bP = *(const bf16x8*)(&smem[raddr]);  // B-op: P[k][n=i]
    bf16x8 a0 = *(const bf16x8*)(Wb + 0 * 8192 + kq * 512);  // A-op: Wh[m=d][k]
    bf16x8 a1 = *(const bf16x8*)(Wb + 1 * 8192 + kq * 512);
    bf16x8 a2 = *(const bf16x8*)(Wb + 2 * 8192 + kq * 512);
    bf16x8 a3 = *(const bf16x8*)(Wb + 3 * 8192 + kq * 512);
    acc0 = __builtin_amdgcn_mfma_f32_16x16x32_bf16(a0, bP, acc0, 0, 0, 0);
    acc1 = __builtin_amdgcn_mfma_f32_16x16x32_bf16(a1, bP, acc1, 0, 0, 0);
    acc2 = __builtin_amdgcn_mfma_f32_16x16x32_bf16(a2, bP, acc2, 0, 0, 0);
    acc3 = __builtin_amdgcn_mfma_f32_16x16x32_bf16(a3, bP, acc3, 0, 0, 0);
    accl = __builtin_amdgcn_mfma_f32_16x16x32_bf16(ones, bP, accl, 0, 0, 0);
  }
  __syncthreads();  // all P reads done before smem reuse

  // ---- combine 4 wave-partials (exact; fixed shift) -> o_part ----
  // C/D layout (m89): col = lane&15 = n = i-sub; row = kg*4+reg = m = d-sub.
  float* lds_o = (float*)smem;            // [4][16][65]
  float* lds_l = (float*)(smem + 16640);  // [4][16]
#pragma unroll
  for (int r = 0; r < 4; ++r) {
    const int d = kg * 4 + r;
    lds_o[wv * 1040 + rsub * 65 + 0 * 16 + d] = acc0[r];
    lds_o[wv * 1040 + rsub * 65 + 1 * 16 + d] = acc1[r];
    lds_o[wv * 1040 + rsub * 65 + 2 * 16 + d] = acc2[r];
    lds_o[wv * 1040 + rsub * 65 + 3 * 16 + d] = acc3[r];
  }
  if (kg == 0) lds_l[wv * 16 + rsub] = accl[0];
  __syncthreads();

  float* opb = o_part + ((size_t)jc * 512 + it) * 1024;
  for (int idx = tid; idx < 1024; idx += 256) {
    const int ii = idx >> 6, d = idx & 63;
    float o = lds_o[0 * 1040 + ii * 65 + d] + lds_o[1 * 1040 + ii * 65 + d] +
              lds_o[2 * 1040 + ii * 65 + d] + lds_o[3 * 1040 + ii * 65 + d];
    opb[idx] = o;
    if (d == 0) {
      l_part[jc * GAT_N + i0 + ii] = lds_l[0 * 16 + ii] + lds_l[1 * 16 + ii] +
                                     lds_l[2 * 16 + ii] + lds_l[3 * 16 + ii];
    }
  }
}

// ---------------------------------------------------------------------------
// Kernel 3 (k_comb): exact merge of 16 j-chunk partials + ELU.
// ---------------------------------------------------------------------------
__global__ __launch_bounds__(256) void k_comb(const float* __restrict__ o_part,
                                              const float* __restrict__ l_part,
                                              float* __restrict__ out) {
  const int idx = blockIdx.x * 256 + threadIdx.x;  // one f32x4 of out
  const int gi = idx >> 4, d4 = (idx & 15) * 4;
  const int it = gi >> 4, ii = gi & 15;
  f32x4 o = {0.f, 0.f, 0.f, 0.f};
  float l = 0.f;
#pragma unroll
  for (int c = 0; c < 16; ++c) {
    o += *(const f32x4*)(o_part + ((size_t)c * 512 + it) * 1024 + ii * 64 + d4);
    l += l_part[c * GAT_N + gi];
  }
  f32x4 v;
#pragma unroll
  for (int e = 0; e < 4; ++e) {
    float val = o[e] / l;
    v[e] = (val > 0.f) ? val : (__expf(val) - 1.f);
  }
  *(f32x4*)(out + (size_t)gi * GAT_D + d4) = v;
}

// ---------------------------------------------------------------------------
extern "C" void kernel_launch(void* const* d_in, const int* in_sizes, int n_in,
                              void* d_out, int out_size, void* d_ws, size_t ws_size,
                              hipStream_t stream) {
  const float* h = (const float*)d_in[0];
  const float* A = (const float*)d_in[1];
  const float* W = (const float*)d_in[2];
  const float* a = (const float*)d_in[3];
  float* out = (float*)d_out;

  // ws: [0,1K) bmax | [4K,+32K) s_src | [36864,+32K) s_dst | [69632,+1M) WhT_f
  //     [1572864,+512K) l_part[16][8192] | [2097152,+32M) o_part[16][512][1024]
  const size_t need = 2097152 + (size_t)16 * 512 * 1024 * 4;
  if (ws_size < need) return;
  float* bmax = (float*)d_ws;
  float* s_src = (float*)((char*)d_ws + 4096);
  float* s_dst = (float*)((char*)d_ws + 36864);
  short* WhT_f = (short*)((char*)d_ws + 69632);
  float* l_part = (float*)((char*)d_ws + 1572864);
  float* o_part = (float*)((char*)d_ws + 2097152);

  k_prep<<<dim3(256), dim3(256), 0, stream>>>(h, W, a, s_src, s_dst, WhT_f, bmax);
  k_attn<<<dim3(8192), dim3(256), 0, stream>>>(A, s_src, s_dst, WhT_f, bmax,
                                               o_part, l_part);
  k_comb<<<dim3(GAT_N * GAT_D / 1024), dim3(256), 0, stream>>>(o_part, l_part, out);
}